// Round 3
// baseline (2867.368 us; speedup 1.0000x reference)
//
#include <hip/hip_runtime.h>
#include <stdint.h>

// SelfRNN: 4-layer tanh RNN, SEQ=256, B=64, H=512.
// Persistent design: weights in VGPRs, 128 WGs (4 layers x 4 batch x 8 col),
// flag-based P2P sync.
// R3: per-access coherence (relaxed agent atomics -> MALL) instead of cache
//     maintenance fences; no LDS -- MFMA A-fragments loaded direct from
//     global; split-phase waits (h-half computed before inp flag arrives).

#define SEQ 256
#define BB  64
#define HH  512
#define NL  4
#define GM  4          // batch groups of 16 rows
#define GN  8          // column groups of 64 cols (16 per wave)
#define WGT 256        // threads per workgroup (4 waves)
#define FLAG_STRIDE 16 // 64B per flag -> no false sharing at coherence point
#define FIDX(t,i,m) ((((t)*NL + (i))*GM + (m)) * FLAG_STRIDE)

typedef __attribute__((ext_vector_type(8))) short bf16x8;
typedef __attribute__((ext_vector_type(4))) float f32x4;
typedef __attribute__((ext_vector_type(4))) int   i32x4;
typedef __attribute__((ext_vector_type(2))) unsigned long long u64x2;

__device__ inline short f2bf(float f){
  uint32_t u = __builtin_bit_cast(uint32_t, f);
  u += 0x7fffu + ((u >> 16) & 1u);   // round-to-nearest-even
  return (short)(u >> 16);
}

__device__ inline float fast_tanh(float xv){
  xv = fminf(15.0f, fmaxf(-15.0f, xv));
  float e = __expf(2.0f * xv);
  return (e - 1.0f) / (e + 1.0f);
}

// RELAXED agent-scope poll: sc-flagged load from coherence point, no cache
// maintenance. Data reads are themselves coherent -> no acquire fence needed.
__device__ inline void spin_ge(int* f, int target){
  int it = 0;
  while (__hip_atomic_load(f, __ATOMIC_RELAXED, __HIP_MEMORY_SCOPE_AGENT) < target){
    __builtin_amdgcn_s_sleep(1);
    if (++it > (1 << 28)) break;   // bailout: wrong-but-terminating beats hang
  }
}

// 16B MFMA A-fragment straight from coherent bf16 buffer (2 x 8B MALL loads)
__device__ inline bf16x8 frag_bf16_coh(const short* p){
  const unsigned long long* q = (const unsigned long long*)p;
  u64x2 v;
  v[0] = __hip_atomic_load(q,     __ATOMIC_RELAXED, __HIP_MEMORY_SCOPE_AGENT);
  v[1] = __hip_atomic_load(q + 1, __ATOMIC_RELAXED, __HIP_MEMORY_SCOPE_AGENT);
  return __builtin_bit_cast(bf16x8, v);
}

// fallback (no ws): coherent f32 fragment -> bf16
__device__ inline bf16x8 frag_f32_coh(const float* p){
  bf16x8 s;
  #pragma unroll
  for (int j = 0; j < 8; ++j){
    float f = __hip_atomic_load(p + j, __ATOMIC_RELAXED, __HIP_MEMORY_SCOPE_AGENT);
    s[j] = f2bf(f);
  }
  return s;
}

// Zero sync flags (d_ws re-poisoned 0xAA every call) + bf16 shadow of x.
__global__ void rnn_prep(const float* __restrict__ x, short* __restrict__ xbf,
                         int* __restrict__ flags, int usews){
  int bid = blockIdx.x, tid = threadIdx.x;
  if (bid == 0){
    i32x4* f4 = (i32x4*)flags;                    // 65536 ints = 16384 int4
    for (int k = tid; k < SEQ*NL*GM*FLAG_STRIDE/4; k += WGT) f4[k] = (i32x4){0,0,0,0};
  }
  if (usews && bid >= 1){
    long base = ((long)(bid - 1) * WGT + tid) * 8;  // 4096 blocks cover 8.39M elems
    f32x4 a = *(const f32x4*)(x + base);
    f32x4 b = *(const f32x4*)(x + base + 4);
    bf16x8 s;
    s[0]=f2bf(a[0]); s[1]=f2bf(a[1]); s[2]=f2bf(a[2]); s[3]=f2bf(a[3]);
    s[4]=f2bf(b[0]); s[5]=f2bf(b[1]); s[6]=f2bf(b[2]); s[7]=f2bf(b[3]);
    *(bf16x8*)(xbf + base) = s;
  }
}

__global__ __launch_bounds__(WGT, 1)
void rnn_main(const float* __restrict__ x,
              const float* __restrict__ w_ih, const float* __restrict__ b_ih,
              const float* __restrict__ w_hh, const float* __restrict__ b_hh,
              float* __restrict__ out,
              short* __restrict__ xbf, short* __restrict__ actbf,
              int* __restrict__ flags, int usews)
{
  const int tid  = threadIdx.x;
  const int wv   = tid >> 6;
  const int lane = tid & 63;
  const int bid  = blockIdx.x;
  const int n = bid >> 4;
  const int i = (bid >> 2) & 3;
  const int m = bid & 3;

  const int l15  = lane & 15;
  const int lq   = lane >> 4;            // quarter-wave 0..3
  const int jcol = n*64 + wv*16 + l15;   // this wave's 16 output cols
  const int ksub = lq * 8;               // k-offset within a 32-wide fragment

  // ---- persistent weight fragments: B-operand, [16 cols x 1024 k] per wave ----
  bf16x8 wf[32];
  {
    const float* wih = w_ih + (long)i*HH*HH + (long)jcol*HH;
    const float* whh = w_hh + (long)i*HH*HH + (long)jcol*HH;
    #pragma unroll
    for (int kk = 0; kk < 16; ++kk){
      const float* p = wih + kk*32 + ksub;
      f32x4 a = *(const f32x4*)p, b = *(const f32x4*)(p + 4);
      bf16x8 s;
      s[0]=f2bf(a[0]); s[1]=f2bf(a[1]); s[2]=f2bf(a[2]); s[3]=f2bf(a[3]);
      s[4]=f2bf(b[0]); s[5]=f2bf(b[1]); s[6]=f2bf(b[2]); s[7]=f2bf(b[3]);
      wf[kk] = s;
      const float* q = whh + kk*32 + ksub;
      f32x4 c = *(const f32x4*)q, d = *(const f32x4*)(q + 4);
      bf16x8 u;
      u[0]=f2bf(c[0]); u[1]=f2bf(c[1]); u[2]=f2bf(c[2]); u[3]=f2bf(c[3]);
      u[4]=f2bf(d[0]); u[5]=f2bf(d[1]); u[6]=f2bf(d[2]); u[7]=f2bf(d[3]);
      wf[kk + 16] = u;
    }
  }
  const float bsum = b_ih[(long)i*HH + jcol] + b_hh[(long)i*HH + jcol];

  float* states = out + (long)SEQ*BB*HH;   // all_states region: [(t*4+i)][b][h]
  const int  bg0   = m * 16;
  const long myrow = bg0 + l15;            // A-row this lane reads (same for all kk)

  for (int t = 0; t < SEQ; ++t){
    f32x4 acc = {0.f, 0.f, 0.f, 0.f};

    // ---- Phase H: own-layer h(t-1) — ready one full cell before inp ----
    if (t > 0){
      if (tid == 0) spin_ge(&flags[FIDX(t-1, i, m)], GN);
      __syncthreads();                     // gate (also blocks compiler hoist)
      bf16x8 af[16];
      if (usews){
        const short* hr = actbf + ((long)((t-1)*NL + i)*BB + myrow)*HH + ksub;
        #pragma unroll
        for (int kk = 0; kk < 16; ++kk) af[kk] = frag_bf16_coh(hr + kk*32);
      } else {
        const float* hr = states + ((long)((t-1)*NL + i)*BB + myrow)*HH + ksub;
        #pragma unroll
        for (int kk = 0; kk < 16; ++kk) af[kk] = frag_f32_coh(hr + kk*32);
      }
      #pragma unroll
      for (int kk = 0; kk < 16; ++kk)
        acc = __builtin_amdgcn_mfma_f32_16x16x32_bf16(af[kk], wf[16+kk], acc, 0, 0, 0);
    }

    // ---- Phase X: inp = x (i==0) or layer i-1 @ t (the frontier dep) ----
    {
      bf16x8 af[16];
      if (i > 0){
        if (tid == 0) spin_ge(&flags[FIDX(t, i-1, m)], GN);
        __syncthreads();
        if (usews){
          const short* pr = actbf + ((long)(t*NL + (i-1))*BB + myrow)*HH + ksub;
          #pragma unroll
          for (int kk = 0; kk < 16; ++kk) af[kk] = frag_bf16_coh(pr + kk*32);
        } else {
          const float* pr = states + ((long)(t*NL + (i-1))*BB + myrow)*HH + ksub;
          #pragma unroll
          for (int kk = 0; kk < 16; ++kk) af[kk] = frag_f32_coh(pr + kk*32);
        }
      } else {
        if (usews){
          const short* xr = xbf + ((long)t*BB + myrow)*HH + ksub;  // plain cached
          #pragma unroll
          for (int kk = 0; kk < 16; ++kk) af[kk] = *(const bf16x8*)(xr + kk*32);
        } else {
          const float* xr = x + ((long)t*BB + myrow)*HH + ksub;
          #pragma unroll
          for (int kk = 0; kk < 16; ++kk){
            f32x4 a = *(const f32x4*)(xr + kk*32), b = *(const f32x4*)(xr + kk*32 + 4);
            bf16x8 s;
            s[0]=f2bf(a[0]); s[1]=f2bf(a[1]); s[2]=f2bf(a[2]); s[3]=f2bf(a[3]);
            s[4]=f2bf(b[0]); s[5]=f2bf(b[1]); s[6]=f2bf(b[2]); s[7]=f2bf(b[3]);
            af[kk] = s;
          }
        }
      }
      #pragma unroll
      for (int kk = 0; kk < 16; ++kk)
        acc = __builtin_amdgcn_mfma_f32_16x16x32_bf16(af[kk], wf[kk], acc, 0, 0, 0);
    }

    // ---- epilogue: bias + tanh; coherent publish of actbf (or states) ----
    #pragma unroll
    for (int r = 0; r < 4; ++r){
      float v = fast_tanh(acc[r] + bsum);   // C/D: col=lane&15, row=lq*4+r (m89)
      int brow = lq*4 + r;
      long srow = (long)(t*NL + i)*BB + bg0 + brow;
      if (usews){
        __builtin_nontemporal_store(v, states + srow*HH + jcol);   // output only
        __hip_atomic_store(actbf + srow*HH + jcol, f2bf(v),
                           __ATOMIC_RELAXED, __HIP_MEMORY_SCOPE_AGENT);
      } else {
        __hip_atomic_store(states + srow*HH + jcol, v,
                           __ATOMIC_RELAXED, __HIP_MEMORY_SCOPE_AGENT);
      }
      if (i == NL-1)
        __builtin_nontemporal_store(v, out + ((long)t*BB + bg0 + brow)*HH + jcol);
    }

    // barrier drains every wave's stores (vmcnt(0) before s_barrier); then one
    // RELEASE add publishes (wbl2 is cheap: L2 dirty set is tiny -- comm
    // stores are write-through, bulk stores are NT).
    __syncthreads();
    if (tid == 0)
      __hip_atomic_fetch_add(&flags[FIDX(t, i, m)], 1,
                             __ATOMIC_RELEASE, __HIP_MEMORY_SCOPE_AGENT);
  }
}

extern "C" void kernel_launch(void* const* d_in, const int* in_sizes, int n_in,
                              void* d_out, int out_size, void* d_ws, size_t ws_size,
                              hipStream_t stream)
{
  (void)in_sizes; (void)n_in; (void)out_size;
  const float* x    = (const float*)d_in[0];
  const float* w_ih = (const float*)d_in[1];
  const float* b_ih = (const float*)d_in[2];
  const float* w_hh = (const float*)d_in[3];
  const float* b_hh = (const float*)d_in[4];
  float* out = (float*)d_out;

  // ws layout: [0,256K) flags (64B-padded) | [256K, +16.8M) x_bf16 | acts_bf16 (67.1MB)
  const size_t FLAGS_BYTES = (size_t)SEQ*NL*GM*FLAG_STRIDE*4;  // 256 KB
  const size_t X_OFF     = FLAGS_BYTES;
  const size_t XBF_BYTES = (size_t)SEQ*BB*HH*2;
  const size_t ACT_OFF   = X_OFF + XBF_BYTES;
  const size_t ACT_BYTES = (size_t)SEQ*NL*BB*HH*2;
  int usews = (ws_size >= ACT_OFF + ACT_BYTES) ? 1 : 0;

  int*   flags = (int*)d_ws;
  short* xbf   = (short*)((char*)d_ws + X_OFF);
  short* actbf = (short*)((char*)d_ws + ACT_OFF);

  int prep_blocks = usews ? (1 + SEQ*BB*HH/(WGT*8)) : 1;   // 4097 or 1
  hipLaunchKernelGGL(rnn_prep, dim3(prep_blocks), dim3(WGT), 0, stream,
                     x, xbf, flags, usews);
  hipLaunchKernelGGL(rnn_main, dim3(NL*GM*GN), dim3(WGT), 0, stream,
                     x, w_ih, b_ih, w_hh, b_hh, out, xbf, actbf, flags, usews);
}